// Round 4
// baseline (31234.262 us; speedup 1.0000x reference)
//
#include <hip/hip_runtime.h>

#define NB 64
#define T 2048
#define D 128
#define H 256
#define H2 512
#define NP 4
#define PAIRS 32
#define CHUNK 4

// workspace: per row 1536 u64 tagged slots:
//   [0..255] c | [256..511] o | [512..1535] hpre (4 parts x 256 partials)
// value = low 32 bits (float bits), seq tag = high 32 bits.
#define ROW_U64 1536
#define WS_NEEDED ((size_t)NB * ROW_U64 * 8)
#define SPIN_LIM (1 << 20)

__device__ __forceinline__ float sigmoid_f(float x) { return 1.f / (1.f + __expf(-x)); }
__device__ __forceinline__ float tanh_f(float x) {
    float e = __expf(2.f * x);
    return 1.f - 2.f / (e + 1.f);
}
__device__ __forceinline__ unsigned long long pack_tag(float v, unsigned int tag) {
    return ((unsigned long long)tag << 32) | (unsigned long long)__float_as_uint(v);
}
__device__ __forceinline__ float poll_tagged(const unsigned long long* __restrict__ ptr,
                                             unsigned int tag, bool& alive) {
    unsigned long long v;
    if (alive) {
        int cnt = 0;
        do {
            v = __hip_atomic_load(ptr, __ATOMIC_RELAXED, __HIP_MEMORY_SCOPE_AGENT);
            if ((unsigned int)(v >> 32) == tag)
                return __uint_as_float((unsigned int)v);
        } while (++cnt < SPIN_LIM);
        alive = false;   // latch: never spin again, accept wrong data over a hang
    }
    v = __hip_atomic_load(ptr, __ATOMIC_RELAXED, __HIP_MEMORY_SCOPE_AGENT);
    return __uint_as_float((unsigned int)v);
}

#define FMA4(A_, S_, W_) \
    A_.x = fmaf(S_, W_.x, A_.x); A_.y = fmaf(S_, W_.y, A_.y); \
    A_.z = fmaf(S_, W_.z, A_.z); A_.w = fmaf(S_, W_.w, A_.w);

// 128 blocks = 32 row-pairs x 4 column-parts; 512 threads; 1 block/CU (LDS-forced).
// Each block serves rows (pair, pair+32) sharing register/LDS-resident weights.
// Per step, per row: 2 tagged HBM-RTT exchanges (c/o, hpre-partials); the two rows'
// phases interleave so one chain of RTTs yields two row-steps.
__global__ __launch_bounds__(512, 2) void scan_kernel(
    const float* __restrict__ x,
    const float* __restrict__ Wi, const float* __restrict__ bi,
    const float* __restrict__ Wf, const float* __restrict__ bf,
    const float* __restrict__ Wc, const float* __restrict__ bc,
    const float* __restrict__ Wo, const float* __restrict__ bo,
    const float* __restrict__ Ui, const float* __restrict__ Uf,
    const float* __restrict__ Uc, const float* __restrict__ Uo,
    const float* __restrict__ K1, const float* __restrict__ kb1,
    const float* __restrict__ K2, const float* __restrict__ kb2,
    const float* __restrict__ gamma, const float* __restrict__ beta,
    float* __restrict__ out,
    unsigned long long* __restrict__ ws)
{
    const int bid  = blockIdx.x;
    const int pair = bid >> 2;
    const int p    = bid & 3;
    const int tid  = threadIdx.x;
    const int rowA = pair;
    const int rowB = pair + PAIRS;

    __shared__ float k2lds[128 * 256];            // 128 KB: K2 rows [p*128,+128), all cols
    __shared__ float xwA[CHUNK][256], xwB[CHUNK][256];   // 8 KB
    __shared__ float red1[2048], red2[2048];      // 16 KB
    __shared__ float hsA[H], hsB[H], csA[H], csB[H], osA[H], osB[H];
    __shared__ float tsA[128], tsB[128];
    // usA == red1[0..255], usB == red1[256..511] (red1 idle in those windows)

    // ---- roles ----
    const int kq  = tid >> 6;                              // 0..7 (wave)
    const int grp = tid & 63;
    const int gG  = grp >> 4;                              // gate 0..3
    const int jG  = (grp & 15) * 4;                        // col-4 within part
    const int ks1 = ((tid >> 6) << 1) | ((tid >> 5) & 1);  // 0..15 (half-wave)
    const int mg1 = tid & 31;                              // K1 col group

    const float* Ug = (gG == 0) ? Ui : (gG == 1) ? Uf : (gG == 2) ? Uc : Uo;
    const float* Wg = (gG == 0) ? Wi : (gG == 1) ? Wf : (gG == 2) ? Wc : Wo;

    // ---- register-resident weights (shared by both rows) ----
    float4 uw[32];
    #pragma unroll
    for (int k = 0; k < 32; ++k)
        uw[k] = *(const float4*)(Ug + (size_t)(kq * 32 + k) * H + p * 64 + jG);

    float4 k1w[16];
    #pragma unroll
    for (int k = 0; k < 16; ++k)
        k1w[k] = *(const float4*)(K1 + (size_t)(ks1 * 16 + k) * H2 + p * 128 + mg1 * 4);

    // ---- K2 row-slice -> LDS ----
    for (int idx = tid; idx < 128 * 64; idx += 512) {
        int k = idx >> 6, jg = (idx & 63) * 4;
        *(float4*)&k2lds[k * 256 + jg] = *(const float4*)(K2 + (size_t)(p * 128 + k) * H + jg);
    }

    // ---- per-role constants (all threads where needed) ----
    float bcat, kb1r, kb2r = 0.f;
    float4 gam4, bet4;
    {
        const int col = tid & 255;
        const int g2 = col >> 6, jj = col & 63;
        const float* bp = (g2 == 0) ? bi : (g2 == 1) ? bf : (g2 == 2) ? bc : bo;
        bcat = bp[p * 64 + jj];
        kb1r = kb1[p * 128 + (tid & 127)];
    }
    if (tid < 256) kb2r = kb2[tid];
    if (tid < 64) {
        gam4 = *(const float4*)(gamma + tid * 4);
        bet4 = *(const float4*)(beta + tid * 4);
    }

    if (tid < 256) { hsA[tid] = 0.f; hsB[tid] = 0.f; }
    float c_regA = 0.f, c_regB = 0.f;   // lane j=tid&63 carries c[p*64+j] (replicated per wave)

    const float* xrowA = x + (size_t)rowA * T * D;
    const float* xrowB = x + (size_t)rowB * T * D;
    float* ybA = out + (size_t)rowA * T * H;
    float* ybB = out + (size_t)rowB * T * H;
    unsigned long long* slotC_A = ws + (size_t)rowA * ROW_U64;
    unsigned long long* slotO_A = slotC_A + 256;
    unsigned long long* slotH_A = slotC_A + 512;
    unsigned long long* slotC_B = ws + (size_t)rowB * ROW_U64;
    unsigned long long* slotO_B = slotC_B + 256;
    unsigned long long* slotH_B = slotC_B + 512;
    const int dqu = __builtin_amdgcn_readfirstlane(kq);   // uniform d-slice -> s_loads for x

    bool alive = true;
    __syncthreads();

    for (int t = 0; t < T; ++t) {
        const int tt4 = t & (CHUNK - 1);
        const unsigned int seq = (unsigned int)(t + 1);

        // ============ phase P: x@W for CHUNK steps, both rows (W loaded once) ============
        if (tt4 == 0) {
            const float* Wp = Wg + p * 64 + jG;
            #pragma unroll
            for (int r4 = 0; r4 < CHUNK; ++r4) {
                float4 aA = make_float4(0.f, 0.f, 0.f, 0.f);
                float4 aB = make_float4(0.f, 0.f, 0.f, 0.f);
                #pragma unroll 4
                for (int dd = 0; dd < 16; ++dd) {
                    const int d = dqu * 16 + dd;
                    float4 w = *(const float4*)(Wp + (size_t)d * H);
                    float xa = xrowA[(size_t)(t + r4) * D + d];   // uniform -> s_load
                    float xb = xrowB[(size_t)(t + r4) * D + d];
                    FMA4(aA, xa, w);
                    FMA4(aB, xb, w);
                }
                *(float4*)&red1[kq * 256 + grp * 4] = aA;
                *(float4*)&red2[kq * 256 + grp * 4] = aB;
                __syncthreads();
                if (tid < 256) {
                    float s = bcat;
                    #pragma unroll
                    for (int q = 0; q < 8; ++q) s += red1[q * 256 + tid];
                    xwA[r4][tid] = s;
                } else {
                    const int col = tid - 256;
                    float s = bcat;
                    #pragma unroll
                    for (int q = 0; q < 8; ++q) s += red2[q * 256 + col];
                    xwB[r4][col] = s;
                }
                __syncthreads();
            }
        }

        // ============ R1: G_A dump ============
        {
            float4 a = make_float4(0.f, 0.f, 0.f, 0.f);
            #pragma unroll
            for (int k4 = 0; k4 < 8; ++k4) {
                float4 hv = *(const float4*)&hsA[kq * 32 + k4 * 4];
                FMA4(a, hv.x, uw[k4 * 4 + 0]);
                FMA4(a, hv.y, uw[k4 * 4 + 1]);
                FMA4(a, hv.z, uw[k4 * 4 + 2]);
                FMA4(a, hv.w, uw[k4 * 4 + 3]);
            }
            *(float4*)&red1[kq * 256 + grp * 4] = a;
        }
        __syncthreads();

        // ============ R2: cellA (redundant all-wave) + publish A ; G_B dump ============
        {
            const int j = tid & 63;
            float si = xwA[tt4][j],       sf = xwA[tt4][64 + j],
                  sg = xwA[tt4][128 + j], so = xwA[tt4][192 + j];
            #pragma unroll
            for (int q = 0; q < 8; ++q) {
                si += red1[q * 256 + j];
                sf += red1[q * 256 + 64 + j];
                sg += red1[q * 256 + 128 + j];
                so += red1[q * 256 + 192 + j];
            }
            float iv = sigmoid_f(si), fv = sigmoid_f(sf);
            float gv = tanh_f(sg),    ov = sigmoid_f(so);
            float c = fmaf(fv, c_regA, iv * gv);
            c_regA = c;
            if (tid >= 448) {   // wave 7 owns LDS slice write + publish
                csA[p * 64 + j] = c;
                osA[p * 64 + j] = ov;
                __hip_atomic_store(slotC_A + p * 64 + j, pack_tag(c, seq),
                                   __ATOMIC_RELAXED, __HIP_MEMORY_SCOPE_AGENT);
                __hip_atomic_store(slotO_A + p * 64 + j, pack_tag(ov, seq),
                                   __ATOMIC_RELAXED, __HIP_MEMORY_SCOPE_AGENT);
            }
        }
        {
            float4 a = make_float4(0.f, 0.f, 0.f, 0.f);
            #pragma unroll
            for (int k4 = 0; k4 < 8; ++k4) {
                float4 hv = *(const float4*)&hsB[kq * 32 + k4 * 4];
                FMA4(a, hv.x, uw[k4 * 4 + 0]);
                FMA4(a, hv.y, uw[k4 * 4 + 1]);
                FMA4(a, hv.z, uw[k4 * 4 + 2]);
                FMA4(a, hv.w, uw[k4 * 4 + 3]);
            }
            *(float4*)&red2[kq * 256 + grp * 4] = a;
        }
        __syncthreads();

        // ============ R3: cellB + publish B ; poll A {c,o} ============
        {
            const int j = tid & 63;
            float si = xwB[tt4][j],       sf = xwB[tt4][64 + j],
                  sg = xwB[tt4][128 + j], so = xwB[tt4][192 + j];
            #pragma unroll
            for (int q = 0; q < 8; ++q) {
                si += red2[q * 256 + j];
                sf += red2[q * 256 + 64 + j];
                sg += red2[q * 256 + 128 + j];
                so += red2[q * 256 + 192 + j];
            }
            float iv = sigmoid_f(si), fv = sigmoid_f(sf);
            float gv = tanh_f(sg),    ov = sigmoid_f(so);
            float c = fmaf(fv, c_regB, iv * gv);
            c_regB = c;
            if (tid >= 448) {
                csB[p * 64 + j] = c;
                osB[p * 64 + j] = ov;
                __hip_atomic_store(slotC_B + p * 64 + j, pack_tag(c, seq),
                                   __ATOMIC_RELAXED, __HIP_MEMORY_SCOPE_AGENT);
                __hip_atomic_store(slotO_B + p * 64 + j, pack_tag(ov, seq),
                                   __ATOMIC_RELAXED, __HIP_MEMORY_SCOPE_AGENT);
            }
        }
        if (tid < 384) {
            const int idx = tid;
            if (idx < 192) {
                const int q  = (p + 1 + (idx >> 6)) & 3;
                const int gj = q * 64 + (idx & 63);
                csA[gj] = poll_tagged(slotC_A + gj, seq, alive);
            } else {
                const int i2 = idx - 192;
                const int q  = (p + 1 + (i2 >> 6)) & 3;
                const int gj = q * 64 + (i2 & 63);
                osA[gj] = poll_tagged(slotO_A + gj, seq, alive);
            }
        }
        __syncthreads();

        // ============ R4: K1_A dump ============
        {
            float4 a = make_float4(0.f, 0.f, 0.f, 0.f);
            #pragma unroll
            for (int k4 = 0; k4 < 4; ++k4) {
                float4 cv = *(const float4*)&csA[ks1 * 16 + k4 * 4];
                FMA4(a, cv.x, k1w[k4 * 4 + 0]);
                FMA4(a, cv.y, k1w[k4 * 4 + 1]);
                FMA4(a, cv.z, k1w[k4 * 4 + 2]);
                FMA4(a, cv.w, k1w[k4 * 4 + 3]);
            }
            *(float4*)&red1[ks1 * 128 + mg1 * 4] = a;
        }
        __syncthreads();

        // ============ R5: tsA reduce ; poll B {c,o} ============
        if (tid < 128) {
            float s = kb1r;
            #pragma unroll
            for (int q = 0; q < 16; ++q) s += red1[q * 128 + tid];
            tsA[tid] = tanh_f(s);
        } else {
            const int idx = tid - 128;     // 0..383
            if (idx < 192) {
                const int q  = (p + 1 + (idx >> 6)) & 3;
                const int gj = q * 64 + (idx & 63);
                csB[gj] = poll_tagged(slotC_B + gj, seq, alive);
            } else {
                const int i2 = idx - 192;
                const int q  = (p + 1 + (i2 >> 6)) & 3;
                const int gj = q * 64 + (i2 & 63);
                osB[gj] = poll_tagged(slotO_B + gj, seq, alive);
            }
        }
        __syncthreads();

        // ============ R6: K2_A dump (8 waves) ; K1_B dump ============
        {
            float4 a = make_float4(0.f, 0.f, 0.f, 0.f);
            #pragma unroll
            for (int kk = 0; kk < 16; kk += 4) {
                float4 tv = *(const float4*)&tsA[kq * 16 + kk];
                float4 w0 = *(const float4*)&k2lds[(kq * 16 + kk + 0) * 256 + grp * 4];
                float4 w1 = *(const float4*)&k2lds[(kq * 16 + kk + 1) * 256 + grp * 4];
                float4 w2 = *(const float4*)&k2lds[(kq * 16 + kk + 2) * 256 + grp * 4];
                float4 w3 = *(const float4*)&k2lds[(kq * 16 + kk + 3) * 256 + grp * 4];
                FMA4(a, tv.x, w0);
                FMA4(a, tv.y, w1);
                FMA4(a, tv.z, w2);
                FMA4(a, tv.w, w3);
            }
            *(float4*)&red1[kq * 256 + grp * 4] = a;
        }
        {
            float4 a = make_float4(0.f, 0.f, 0.f, 0.f);
            #pragma unroll
            for (int k4 = 0; k4 < 4; ++k4) {
                float4 cv = *(const float4*)&csB[ks1 * 16 + k4 * 4];
                FMA4(a, cv.x, k1w[k4 * 4 + 0]);
                FMA4(a, cv.y, k1w[k4 * 4 + 1]);
                FMA4(a, cv.z, k1w[k4 * 4 + 2]);
                FMA4(a, cv.w, k1w[k4 * 4 + 3]);
            }
            *(float4*)&red2[ks1 * 128 + mg1 * 4] = a;
        }
        __syncthreads();

        // ============ R7: hpreA reduce + publish ; tsB reduce ============
        float phA = 0.f;
        if (tid < 256) {
            #pragma unroll
            for (int q = 0; q < 8; ++q) phA += red1[q * 256 + tid];
            __hip_atomic_store(slotH_A + p * 256 + tid, pack_tag(phA, seq),
                               __ATOMIC_RELAXED, __HIP_MEMORY_SCOPE_AGENT);
        } else if (tid < 384) {
            const int col = tid - 256;    // 0..127
            float s = kb1r;
            #pragma unroll
            for (int q = 0; q < 16; ++q) s += red2[q * 128 + col];
            tsB[col] = tanh_f(s);
        }
        __syncthreads();

        // ============ R8: poll hpreA + usA ; K2_B dump (waves 4-7, 32k each) ============
        if (tid < 256) {
            const unsigned long long* q1 = slotH_A + (((p + 1) & 3) << 8) + tid;
            const unsigned long long* q2 = slotH_A + (((p + 2) & 3) << 8) + tid;
            const unsigned long long* q3 = slotH_A + (((p + 3) & 3) << 8) + tid;
            unsigned long long v1 = 0, v2 = 0, v3 = 0;
            bool d1 = false, d2 = false, d3 = false;
            int cnt = 0;
            const int lim = alive ? SPIN_LIM : 2;
            while (true) {
                if (!d1) v1 = __hip_atomic_load(q1, __ATOMIC_RELAXED, __HIP_MEMORY_SCOPE_AGENT);
                if (!d2) v2 = __hip_atomic_load(q2, __ATOMIC_RELAXED, __HIP_MEMORY_SCOPE_AGENT);
                if (!d3) v3 = __hip_atomic_load(q3, __ATOMIC_RELAXED, __HIP_MEMORY_SCOPE_AGENT);
                d1 = d1 | ((unsigned int)(v1 >> 32) == seq);
                d2 = d2 | ((unsigned int)(v2 >> 32) == seq);
                d3 = d3 | ((unsigned int)(v3 >> 32) == seq);
                if (d1 & d2 & d3) break;
                if (++cnt > lim) { alive = false; break; }
            }
            float hp = phA + __uint_as_float((unsigned int)v1)
                           + __uint_as_float((unsigned int)v2)
                           + __uint_as_float((unsigned int)v3) + kb2r;
            red1[tid] = osA[tid] * tanh_f(hp);        // usA
        } else {
            const int w4 = kq - 4;                    // 0..3
            float4 a = make_float4(0.f, 0.f, 0.f, 0.f);
            #pragma unroll
            for (int kk = 0; kk < 32; kk += 4) {
                float4 tv = *(const float4*)&tsB[w4 * 32 + kk];
                float4 w0 = *(const float4*)&k2lds[(w4 * 32 + kk + 0) * 256 + grp * 4];
                float4 w1 = *(const float4*)&k2lds[(w4 * 32 + kk + 1) * 256 + grp * 4];
                float4 w2 = *(const float4*)&k2lds[(w4 * 32 + kk + 2) * 256 + grp * 4];
                float4 w3 = *(const float4*)&k2lds[(w4 * 32 + kk + 3) * 256 + grp * 4];
                FMA4(a, tv.x, w0);
                FMA4(a, tv.y, w1);
                FMA4(a, tv.z, w2);
                FMA4(a, tv.w, w3);
            }
            *(float4*)&red2[w4 * 256 + grp * 4] = a;
        }
        __syncthreads();

        // ============ R9: hpreB reduce + publish ; LN_A ============
        float phB = 0.f;
        if (tid < 256) {
            #pragma unroll
            for (int q = 0; q < 4; ++q) phB += red2[q * 256 + tid];
            __hip_atomic_store(slotH_B + p * 256 + tid, pack_tag(phB, seq),
                               __ATOMIC_RELAXED, __HIP_MEMORY_SCOPE_AGENT);
        }
        if (tid < 64) {
            float4 u4 = *(const float4*)&red1[tid * 4];    // usA
            float s1 = u4.x + u4.y + u4.z + u4.w;
            float s2 = u4.x * u4.x + u4.y * u4.y + u4.z * u4.z + u4.w * u4.w;
            #pragma unroll
            for (int off = 32; off > 0; off >>= 1) {
                s1 += __shfl_xor(s1, off);
                s2 += __shfl_xor(s2, off);
            }
            float mu   = s1 * (1.f / 256.f);
            float var  = fmaf(-mu, mu, s2 * (1.f / 256.f));
            float rstd = rsqrtf(var + 1e-5f);
            float4 hn;
            hn.x = (u4.x - mu) * rstd * gam4.x + bet4.x;
            hn.y = (u4.y - mu) * rstd * gam4.y + bet4.y;
            hn.z = (u4.z - mu) * rstd * gam4.z + bet4.z;
            hn.w = (u4.w - mu) * rstd * gam4.w + bet4.w;
            *(float4*)&hsA[tid * 4] = hn;
            if ((tid >> 4) == p) {
                *(float4*)(ybA + (size_t)t * H + tid * 4) = hn;
                if (t == T - 1) {
                    *(float4*)(out + (size_t)NB * T * H + (size_t)rowA * H + tid * 4) = hn;
                    float4 c4 = *(const float4*)&csA[tid * 4];
                    *(float4*)(out + (size_t)NB * T * H + (size_t)NB * H + (size_t)rowA * H + tid * 4) = c4;
                }
            }
        }
        __syncthreads();

        // ============ R10: poll hpreB + usB ============
        if (tid < 256) {
            const unsigned long long* q1 = slotH_B + (((p + 1) & 3) << 8) + tid;
            const unsigned long long* q2 = slotH_B + (((p + 2) & 3) << 8) + tid;
            const unsigned long long* q3 = slotH_B + (((p + 3) & 3) << 8) + tid;
            unsigned long long v1 = 0, v2 = 0, v3 = 0;
            bool d1 = false, d2 = false, d3 = false;
            int cnt = 0;
            const int lim = alive ? SPIN_LIM : 2;
            while (true) {
                if (!d1) v1 = __hip_atomic_load(q1, __ATOMIC_RELAXED, __HIP_MEMORY_SCOPE_AGENT);
                if (!d2) v2 = __hip_atomic_load(q2, __ATOMIC_RELAXED, __HIP_MEMORY_SCOPE_AGENT);
                if (!d3) v3 = __hip_atomic_load(q3, __ATOMIC_RELAXED, __HIP_MEMORY_SCOPE_AGENT);
                d1 = d1 | ((unsigned int)(v1 >> 32) == seq);
                d2 = d2 | ((unsigned int)(v2 >> 32) == seq);
                d3 = d3 | ((unsigned int)(v3 >> 32) == seq);
                if (d1 & d2 & d3) break;
                if (++cnt > lim) { alive = false; break; }
            }
            float hp = phB + __uint_as_float((unsigned int)v1)
                           + __uint_as_float((unsigned int)v2)
                           + __uint_as_float((unsigned int)v3) + kb2r;
            red1[256 + tid] = osB[tid] * tanh_f(hp);   // usB
        }
        __syncthreads();

        // ============ R11: LN_B ============
        if (tid < 64) {
            float4 u4 = *(const float4*)&red1[256 + tid * 4];   // usB
            float s1 = u4.x + u4.y + u4.z + u4.w;
            float s2 = u4.x * u4.x + u4.y * u4.y + u4.z * u4.z + u4.w * u4.w;
            #pragma unroll
            for (int off = 32; off > 0; off >>= 1) {
                s1 += __shfl_xor(s1, off);
                s2 += __shfl_xor(s2, off);
            }
            float mu   = s1 * (1.f / 256.f);
            float var  = fmaf(-mu, mu, s2 * (1.f / 256.f));
            float rstd = rsqrtf(var + 1e-5f);
            float4 hn;
            hn.x = (u4.x - mu) * rstd * gam4.x + bet4.x;
            hn.y = (u4.y - mu) * rstd * gam4.y + bet4.y;
            hn.z = (u4.z - mu) * rstd * gam4.z + bet4.z;
            hn.w = (u4.w - mu) * rstd * gam4.w + bet4.w;
            *(float4*)&hsB[tid * 4] = hn;
            if ((tid >> 4) == p) {
                *(float4*)(ybB + (size_t)t * H + tid * 4) = hn;
                if (t == T - 1) {
                    *(float4*)(out + (size_t)NB * T * H + (size_t)rowB * H + tid * 4) = hn;
                    float4 c4 = *(const float4*)&csB[tid * 4];
                    *(float4*)(out + (size_t)NB * T * H + (size_t)NB * H + (size_t)rowB * H + tid * 4) = c4;
                }
            }
        }
        __syncthreads();   // hsB/red1 ready for next step
    }
}

extern "C" void kernel_launch(void* const* d_in, const int* in_sizes, int n_in,
                              void* d_out, int out_size, void* d_ws, size_t ws_size,
                              hipStream_t stream) {
    (void)in_sizes; (void)n_in; (void)out_size;
    if (ws_size < WS_NEEDED) return;

    const float* x     = (const float*)d_in[0];
    const float* Wi    = (const float*)d_in[1];
    const float* bi    = (const float*)d_in[2];
    const float* Wf    = (const float*)d_in[3];
    const float* bf    = (const float*)d_in[4];
    const float* Wc    = (const float*)d_in[5];
    const float* bc    = (const float*)d_in[6];
    const float* Wo    = (const float*)d_in[7];
    const float* bo    = (const float*)d_in[8];
    const float* Ui    = (const float*)d_in[9];
    const float* Uf    = (const float*)d_in[10];
    const float* Uc    = (const float*)d_in[11];
    const float* Uo    = (const float*)d_in[12];
    const float* K1    = (const float*)d_in[13];
    const float* kb1   = (const float*)d_in[14];
    const float* K2    = (const float*)d_in[15];
    const float* kb2   = (const float*)d_in[16];
    const float* gamma = (const float*)d_in[17];
    const float* beta  = (const float*)d_in[18];
    float* out = (float*)d_out;

    scan_kernel<<<dim3(PAIRS * NP), dim3(512), 0, stream>>>(
        x, Wi, bi, Wf, bf, Wc, bc, Wo, bo,
        Ui, Uf, Uc, Uo, K1, kb1, K2, kb2, gamma, beta, out,
        (unsigned long long*)d_ws);
}

// Round 5
// 26532.553 us; speedup vs baseline: 1.1772x; 1.1772x over previous
//
#include <hip/hip_runtime.h>

#define NB 64
#define T 2048
#define D 128
#define H 256
#define H2 512
#define NP 4
#define PAIRS 32
#define CHUNK 4

// workspace: per row 1536 u64 tagged slots:
//   [0..255] c | [256..511] o | [512..1535] hpre (4 parts x 256 partials)
// value = low 32 bits (float bits), seq tag = high 32 bits.
#define ROW_U64 1536
#define WS_NEEDED ((size_t)NB * ROW_U64 * 8)
#define SPIN_LIM (1 << 20)

__device__ __forceinline__ float sigmoid_f(float x) { return 1.f / (1.f + __expf(-x)); }
__device__ __forceinline__ float tanh_f(float x) {
    float e = __expf(2.f * x);
    return 1.f - 2.f / (e + 1.f);
}
__device__ __forceinline__ unsigned long long pack_tag(float v, unsigned int tag) {
    return ((unsigned long long)tag << 32) | (unsigned long long)__float_as_uint(v);
}

#define FMA4(A_, S_, W_) \
    A_.x = fmaf(S_, W_.x, A_.x); A_.y = fmaf(S_, W_.y, A_.y); \
    A_.z = fmaf(S_, W_.z, A_.z); A_.w = fmaf(S_, W_.w, A_.w);

// 128 blocks = 32 row-pairs x 4 column-parts; 512 threads; 1 block/CU (LDS-forced).
// Two rows (pair, pair+32) share register/LDS weights. Per step only TWO wait
// phases, each a MERGED dual-row poll (waits overlap instead of serializing —
// round-4's failure was 4 disjoint wait phases).
__global__ __launch_bounds__(512, 2) void scan_kernel(
    const float* __restrict__ x,
    const float* __restrict__ Wi, const float* __restrict__ bi,
    const float* __restrict__ Wf, const float* __restrict__ bf,
    const float* __restrict__ Wc, const float* __restrict__ bc,
    const float* __restrict__ Wo, const float* __restrict__ bo,
    const float* __restrict__ Ui, const float* __restrict__ Uf,
    const float* __restrict__ Uc, const float* __restrict__ Uo,
    const float* __restrict__ K1, const float* __restrict__ kb1,
    const float* __restrict__ K2, const float* __restrict__ kb2,
    const float* __restrict__ gamma, const float* __restrict__ beta,
    float* __restrict__ out,
    unsigned long long* __restrict__ ws)
{
    const int bid  = blockIdx.x;
    const int pair = bid >> 2;
    const int p    = bid & 3;
    const int tid  = threadIdx.x;
    const int rowA = pair;
    const int rowB = pair + PAIRS;

    __shared__ float k2lds[128 * 256];                 // 128 KB K2 rows [p*128,+128)
    __shared__ float xwA[CHUNK][256], xwB[CHUNK][256]; // 8 KB
    __shared__ float red1[2048], red2[2048];           // 16 KB
    __shared__ float hsA[H], hsB[H], csA[H], csB[H], osA[H], osB[H];
    __shared__ float tsA[128], tsB[128];

    // ---- roles ----
    const int kq  = tid >> 6;                              // 0..7 (wave)
    const int grp = tid & 63;
    const int gG  = grp >> 4;                              // gate 0..3
    const int jG  = (grp & 15) * 4;                        // col-4 within part
    const int ks1 = ((tid >> 6) << 1) | ((tid >> 5) & 1);  // 0..15 (half-wave)
    const int mg1 = tid & 31;                              // K1 col group

    const float* Ug = (gG == 0) ? Ui : (gG == 1) ? Uf : (gG == 2) ? Uc : Uo;
    const float* Wg = (gG == 0) ? Wi : (gG == 1) ? Wf : (gG == 2) ? Wc : Wo;

    // ---- register-resident weights (shared by both rows) ----
    float4 uw[32];
    #pragma unroll
    for (int k = 0; k < 32; ++k)
        uw[k] = *(const float4*)(Ug + (size_t)(kq * 32 + k) * H + p * 64 + jG);

    float4 k1w[16];
    #pragma unroll
    for (int k = 0; k < 16; ++k)
        k1w[k] = *(const float4*)(K1 + (size_t)(ks1 * 16 + k) * H2 + p * 128 + mg1 * 4);

    // ---- K2 row-slice -> LDS ----
    for (int idx = tid; idx < 128 * 64; idx += 512) {
        int k = idx >> 6, jg = (idx & 63) * 4;
        *(float4*)&k2lds[k * 256 + jg] = *(const float4*)(K2 + (size_t)(p * 128 + k) * H + jg);
    }

    // ---- per-role constants ----
    float bcat, kb1r, kb2r;
    float4 gam4, bet4;
    {
        const int col = tid & 255;
        const int g2 = col >> 6, jj = col & 63;
        const float* bp = (g2 == 0) ? bi : (g2 == 1) ? bf : (g2 == 2) ? bc : bo;
        bcat = bp[p * 64 + jj];
        kb1r = kb1[p * 128 + (tid & 127)];
        kb2r = kb2[col];
    }
    if (tid < 128) {
        gam4 = *(const float4*)(gamma + (tid & 63) * 4);
        bet4 = *(const float4*)(beta + (tid & 63) * 4);
    }

    if (tid < 256) { hsA[tid] = 0.f; hsB[tid] = 0.f; }
    float c_regA = 0.f, c_regB = 0.f;   // A live in tid<256, B in tid>=256

    const float* xrowA = x + (size_t)rowA * T * D;
    const float* xrowB = x + (size_t)rowB * T * D;
    float* ybA = out + (size_t)rowA * T * H;
    float* ybB = out + (size_t)rowB * T * H;
    unsigned long long* slotC_A = ws + (size_t)rowA * ROW_U64;
    unsigned long long* slotO_A = slotC_A + 256;
    unsigned long long* slotH_A = slotC_A + 512;
    unsigned long long* slotC_B = ws + (size_t)rowB * ROW_U64;
    unsigned long long* slotO_B = slotC_B + 256;
    unsigned long long* slotH_B = slotC_B + 512;
    const int dqu = __builtin_amdgcn_readfirstlane(kq);

    bool alive = true;
    __syncthreads();

    // ---- prefill xw for chunk 0 (both rows) ----
    #pragma unroll
    for (int r4 = 0; r4 < CHUNK; ++r4) {
        float4 aA = make_float4(0.f, 0.f, 0.f, 0.f);
        float4 aB = make_float4(0.f, 0.f, 0.f, 0.f);
        const float* Wp = Wg + p * 64 + jG;
        #pragma unroll 4
        for (int dd = 0; dd < 16; ++dd) {
            const int d = dqu * 16 + dd;
            float4 w = *(const float4*)(Wp + (size_t)d * H);
            float xa = xrowA[(size_t)r4 * D + d];
            float xb = xrowB[(size_t)r4 * D + d];
            FMA4(aA, xa, w);
            FMA4(aB, xb, w);
        }
        *(float4*)&red1[kq * 256 + grp * 4] = aA;
        *(float4*)&red2[kq * 256 + grp * 4] = aB;
        __syncthreads();
        if (tid < 256) {
            float s = bcat;
            #pragma unroll
            for (int q = 0; q < 8; ++q) s += red1[q * 256 + tid];
            xwA[r4][tid] = s;
        } else {
            const int col = tid - 256;
            float s = bcat;
            #pragma unroll
            for (int q = 0; q < 8; ++q) s += red2[q * 256 + col];
            xwB[r4][col] = s;
        }
        __syncthreads();
    }

    for (int t = 0; t < T; ++t) {
        const int tt4 = t & (CHUNK - 1);
        const unsigned int seq = (unsigned int)(t + 1);
        const int nxt  = (t & ~(CHUNK - 1)) + CHUNK;    // next chunk base
        const bool donx = (nxt < T);
        const int tx = nxt + tt4;                       // step whose xw we prefill

        // ============ P1: G_A dump ; G_B dump ============
        {
            float4 a1 = make_float4(0.f, 0.f, 0.f, 0.f);
            float4 a2 = make_float4(0.f, 0.f, 0.f, 0.f);
            #pragma unroll
            for (int k4 = 0; k4 < 8; ++k4) {
                float4 hvA = *(const float4*)&hsA[kq * 32 + k4 * 4];
                float4 hvB = *(const float4*)&hsB[kq * 32 + k4 * 4];
                FMA4(a1, hvA.x, uw[k4 * 4 + 0]);
                FMA4(a1, hvA.y, uw[k4 * 4 + 1]);
                FMA4(a1, hvA.z, uw[k4 * 4 + 2]);
                FMA4(a1, hvA.w, uw[k4 * 4 + 3]);
                FMA4(a2, hvB.x, uw[k4 * 4 + 0]);
                FMA4(a2, hvB.y, uw[k4 * 4 + 1]);
                FMA4(a2, hvB.z, uw[k4 * 4 + 2]);
                FMA4(a2, hvB.w, uw[k4 * 4 + 3]);
            }
            *(float4*)&red1[kq * 256 + grp * 4] = a1;
            *(float4*)&red2[kq * 256 + grp * 4] = a2;
        }
        __syncthreads();

        // ============ P2: cell_A (tid<256) ; cell_B (tid>=256) + both publishes ============
        {
            const int j = tid & 63;
            if (tid < 256) {
                float si = xwA[tt4][j],       sf = xwA[tt4][64 + j],
                      sg = xwA[tt4][128 + j], so = xwA[tt4][192 + j];
                #pragma unroll
                for (int q = 0; q < 8; ++q) {
                    si += red1[q * 256 + j];
                    sf += red1[q * 256 + 64 + j];
                    sg += red1[q * 256 + 128 + j];
                    so += red1[q * 256 + 192 + j];
                }
                float iv = sigmoid_f(si), fv = sigmoid_f(sf);
                float gv = tanh_f(sg),    ov = sigmoid_f(so);
                float c = fmaf(fv, c_regA, iv * gv);
                c_regA = c;
                if (tid >= 192) {            // wave 3 publishes row A
                    csA[p * 64 + j] = c;
                    osA[p * 64 + j] = ov;
                    __hip_atomic_store(slotC_A + p * 64 + j, pack_tag(c, seq),
                                       __ATOMIC_RELAXED, __HIP_MEMORY_SCOPE_AGENT);
                    __hip_atomic_store(slotO_A + p * 64 + j, pack_tag(ov, seq),
                                       __ATOMIC_RELAXED, __HIP_MEMORY_SCOPE_AGENT);
                }
            } else {
                float si = xwB[tt4][j],       sf = xwB[tt4][64 + j],
                      sg = xwB[tt4][128 + j], so = xwB[tt4][192 + j];
                #pragma unroll
                for (int q = 0; q < 8; ++q) {
                    si += red2[q * 256 + j];
                    sf += red2[q * 256 + 64 + j];
                    sg += red2[q * 256 + 128 + j];
                    so += red2[q * 256 + 192 + j];
                }
                float iv = sigmoid_f(si), fv = sigmoid_f(sf);
                float gv = tanh_f(sg),    ov = sigmoid_f(so);
                float c = fmaf(fv, c_regB, iv * gv);
                c_regB = c;
                if (tid >= 448) {            // wave 7 publishes row B
                    csB[p * 64 + j] = c;
                    osB[p * 64 + j] = ov;
                    __hip_atomic_store(slotC_B + p * 64 + j, pack_tag(c, seq),
                                       __ATOMIC_RELAXED, __HIP_MEMORY_SCOPE_AGENT);
                    __hip_atomic_store(slotO_B + p * 64 + j, pack_tag(ov, seq),
                                       __ATOMIC_RELAXED, __HIP_MEMORY_SCOPE_AGENT);
                }
            }
        }
        __syncthreads();

        // ============ P3: next-chunk x@W slice, both rows (RTT coverage) ============
        if (donx) {
            float4 aA = make_float4(0.f, 0.f, 0.f, 0.f);
            float4 aB = make_float4(0.f, 0.f, 0.f, 0.f);
            const float* Wp = Wg + p * 64 + jG;
            #pragma unroll 4
            for (int dd = 0; dd < 16; ++dd) {
                const int d = dqu * 16 + dd;
                float4 w = *(const float4*)(Wp + (size_t)d * H);
                float xa = xrowA[(size_t)tx * D + d];
                float xb = xrowB[(size_t)tx * D + d];
                FMA4(aA, xa, w);
                FMA4(aB, xb, w);
            }
            *(float4*)&red1[kq * 256 + grp * 4] = aA;
            *(float4*)&red2[kq * 256 + grp * 4] = aB;
        }
        __syncthreads();

        // ============ P4: MERGED c/o polls (A and B overlap) + xw reduces ============
        {
            const unsigned long long* pA = 0; float* dstA = 0;
            if (tid < 384) {
                if (tid < 192) {
                    int q = (p + 1 + (tid >> 6)) & 3; int gj = q * 64 + (tid & 63);
                    pA = slotC_A + gj; dstA = &csA[gj];
                } else {
                    int i2 = tid - 192;
                    int q = (p + 1 + (i2 >> 6)) & 3; int gj = q * 64 + (i2 & 63);
                    pA = slotO_A + gj; dstA = &osA[gj];
                }
            }
            const unsigned long long* pB = 0; float* dstB = 0;
            if (tid >= 128) {
                int i3 = tid - 128;
                if (i3 < 192) {
                    int q = (p + 1 + (i3 >> 6)) & 3; int gj = q * 64 + (i3 & 63);
                    pB = slotC_B + gj; dstB = &csB[gj];
                } else {
                    int i2 = i3 - 192;
                    int q = (p + 1 + (i2 >> 6)) & 3; int gj = q * 64 + (i2 & 63);
                    pB = slotO_B + gj; dstB = &osB[gj];
                }
            }
            bool dA = (pA == 0), dB = (pB == 0);
            int cnt = 0;
            const int lim = alive ? SPIN_LIM : 2;
            while (!(dA && dB)) {
                unsigned long long v;
                if (!dA) {
                    v = __hip_atomic_load(pA, __ATOMIC_RELAXED, __HIP_MEMORY_SCOPE_AGENT);
                    if ((unsigned int)(v >> 32) == seq) { *dstA = __uint_as_float((unsigned int)v); dA = true; }
                }
                if (!dB) {
                    v = __hip_atomic_load(pB, __ATOMIC_RELAXED, __HIP_MEMORY_SCOPE_AGENT);
                    if ((unsigned int)(v >> 32) == seq) { *dstB = __uint_as_float((unsigned int)v); dB = true; }
                }
                if (++cnt > lim) {
                    alive = false;
                    if (!dA) {
                        v = __hip_atomic_load(pA, __ATOMIC_RELAXED, __HIP_MEMORY_SCOPE_AGENT);
                        *dstA = __uint_as_float((unsigned int)v);
                    }
                    if (!dB) {
                        v = __hip_atomic_load(pB, __ATOMIC_RELAXED, __HIP_MEMORY_SCOPE_AGENT);
                        *dstB = __uint_as_float((unsigned int)v);
                    }
                    break;
                }
            }
            if (donx) {
                if (tid < 256) {
                    float s = bcat;
                    #pragma unroll
                    for (int q = 0; q < 8; ++q) s += red1[q * 256 + tid];
                    xwA[tt4][tid] = s;
                } else {
                    const int col = tid - 256;
                    float s = bcat;
                    #pragma unroll
                    for (int q = 0; q < 8; ++q) s += red2[q * 256 + col];
                    xwB[tt4][col] = s;
                }
            }
        }
        __syncthreads();

        // ============ P5: K1_A dump ============
        {
            float4 a = make_float4(0.f, 0.f, 0.f, 0.f);
            #pragma unroll
            for (int k4 = 0; k4 < 4; ++k4) {
                float4 cv = *(const float4*)&csA[ks1 * 16 + k4 * 4];
                FMA4(a, cv.x, k1w[k4 * 4 + 0]);
                FMA4(a, cv.y, k1w[k4 * 4 + 1]);
                FMA4(a, cv.z, k1w[k4 * 4 + 2]);
                FMA4(a, cv.w, k1w[k4 * 4 + 3]);
            }
            *(float4*)&red1[ks1 * 128 + mg1 * 4] = a;
        }
        __syncthreads();

        // ============ P6: ts_A reduce (tid<128) ; K1_B dump (all) ============
        if (tid < 128) {
            float s = kb1r;
            #pragma unroll
            for (int q = 0; q < 16; ++q) s += red1[q * 128 + tid];
            tsA[tid] = tanh_f(s);
        }
        {
            float4 a = make_float4(0.f, 0.f, 0.f, 0.f);
            #pragma unroll
            for (int k4 = 0; k4 < 4; ++k4) {
                float4 cv = *(const float4*)&csB[ks1 * 16 + k4 * 4];
                FMA4(a, cv.x, k1w[k4 * 4 + 0]);
                FMA4(a, cv.y, k1w[k4 * 4 + 1]);
                FMA4(a, cv.z, k1w[k4 * 4 + 2]);
                FMA4(a, cv.w, k1w[k4 * 4 + 3]);
            }
            *(float4*)&red2[ks1 * 128 + mg1 * 4] = a;
        }
        __syncthreads();

        // ============ P7: ts_B reduce (tid 128..255) ; K2_A dump (all) ============
        if (tid >= 128 && tid < 256) {
            const int col = tid - 128;
            float s = kb1r;
            #pragma unroll
            for (int q = 0; q < 16; ++q) s += red2[q * 128 + col];
            tsB[col] = tanh_f(s);
        }
        {
            float4 a = make_float4(0.f, 0.f, 0.f, 0.f);
            #pragma unroll
            for (int kk = 0; kk < 16; kk += 4) {
                float4 tv = *(const float4*)&tsA[kq * 16 + kk];
                float4 w0 = *(const float4*)&k2lds[(kq * 16 + kk + 0) * 256 + grp * 4];
                float4 w1 = *(const float4*)&k2lds[(kq * 16 + kk + 1) * 256 + grp * 4];
                float4 w2 = *(const float4*)&k2lds[(kq * 16 + kk + 2) * 256 + grp * 4];
                float4 w3 = *(const float4*)&k2lds[(kq * 16 + kk + 3) * 256 + grp * 4];
                FMA4(a, tv.x, w0);
                FMA4(a, tv.y, w1);
                FMA4(a, tv.z, w2);
                FMA4(a, tv.w, w3);
            }
            *(float4*)&red1[kq * 256 + grp * 4] = a;
        }
        __syncthreads();

        // ============ P8: hpre_A reduce+publish (tid<256) ; K2_B dump (all) ============
        float phA = 0.f;
        if (tid < 256) {
            #pragma unroll
            for (int q = 0; q < 8; ++q) phA += red1[q * 256 + tid];
            __hip_atomic_store(slotH_A + p * 256 + tid, pack_tag(phA, seq),
                               __ATOMIC_RELAXED, __HIP_MEMORY_SCOPE_AGENT);
        }
        {
            float4 a = make_float4(0.f, 0.f, 0.f, 0.f);
            #pragma unroll
            for (int kk = 0; kk < 16; kk += 4) {
                float4 tv = *(const float4*)&tsB[kq * 16 + kk];
                float4 w0 = *(const float4*)&k2lds[(kq * 16 + kk + 0) * 256 + grp * 4];
                float4 w1 = *(const float4*)&k2lds[(kq * 16 + kk + 1) * 256 + grp * 4];
                float4 w2 = *(const float4*)&k2lds[(kq * 16 + kk + 2) * 256 + grp * 4];
                float4 w3 = *(const float4*)&k2lds[(kq * 16 + kk + 3) * 256 + grp * 4];
                FMA4(a, tv.x, w0);
                FMA4(a, tv.y, w1);
                FMA4(a, tv.z, w2);
                FMA4(a, tv.w, w3);
            }
            *(float4*)&red2[kq * 256 + grp * 4] = a;
        }
        __syncthreads();

        // ============ P9: hpre_B reduce+publish (tid>=256) ============
        float phB = 0.f;
        if (tid >= 256) {
            const int col = tid - 256;
            #pragma unroll
            for (int q = 0; q < 8; ++q) phB += red2[q * 256 + col];
            __hip_atomic_store(slotH_B + p * 256 + col, pack_tag(phB, seq),
                               __ATOMIC_RELAXED, __HIP_MEMORY_SCOPE_AGENT);
        }
        __syncthreads();

        // ============ P10: MERGED hpre polls -> u (A: tid<256, B: tid>=256) ============
        {
            const unsigned long long* q1;
            const unsigned long long* q2;
            const unsigned long long* q3;
            float ph, ov;
            int col;
            if (tid < 256) {
                col = tid; ph = phA; ov = osA[col];
                q1 = slotH_A + (((p + 1) & 3) << 8) + col;
                q2 = slotH_A + (((p + 2) & 3) << 8) + col;
                q3 = slotH_A + (((p + 3) & 3) << 8) + col;
            } else {
                col = tid - 256; ph = phB; ov = osB[col];
                q1 = slotH_B + (((p + 1) & 3) << 8) + col;
                q2 = slotH_B + (((p + 2) & 3) << 8) + col;
                q3 = slotH_B + (((p + 3) & 3) << 8) + col;
            }
            unsigned long long v1 = 0, v2 = 0, v3 = 0;
            bool d1 = false, d2 = false, d3 = false;
            int cnt = 0;
            const int lim = alive ? SPIN_LIM : 2;
            while (true) {
                if (!d1) v1 = __hip_atomic_load(q1, __ATOMIC_RELAXED, __HIP_MEMORY_SCOPE_AGENT);
                if (!d2) v2 = __hip_atomic_load(q2, __ATOMIC_RELAXED, __HIP_MEMORY_SCOPE_AGENT);
                if (!d3) v3 = __hip_atomic_load(q3, __ATOMIC_RELAXED, __HIP_MEMORY_SCOPE_AGENT);
                d1 = d1 | ((unsigned int)(v1 >> 32) == seq);
                d2 = d2 | ((unsigned int)(v2 >> 32) == seq);
                d3 = d3 | ((unsigned int)(v3 >> 32) == seq);
                if (d1 & d2 & d3) break;
                if (++cnt > lim) { alive = false; break; }
            }
            float hp = ph + __uint_as_float((unsigned int)v1)
                          + __uint_as_float((unsigned int)v2)
                          + __uint_as_float((unsigned int)v3) + kb2r;
            red1[(tid < 256 ? 0 : 256) + col] = ov * tanh_f(hp);   // uA | uB
        }
        __syncthreads();

        // ============ P11: LN_A (lanes 0-63) ; LN_B (lanes 64-127) ============
        if (tid < 128) {
            const int l = tid & 63;
            const int base = (tid < 64) ? 0 : 256;
            float4 u4 = *(const float4*)&red1[base + l * 4];
            float s1 = u4.x + u4.y + u4.z + u4.w;
            float s2 = u4.x * u4.x + u4.y * u4.y + u4.z * u4.z + u4.w * u4.w;
            #pragma unroll
            for (int off = 32; off > 0; off >>= 1) {
                s1 += __shfl_xor(s1, off);
                s2 += __shfl_xor(s2, off);
            }
            float mu   = s1 * (1.f / 256.f);
            float var  = fmaf(-mu, mu, s2 * (1.f / 256.f));
            float rstd = rsqrtf(var + 1e-5f);
            float4 hn;
            hn.x = (u4.x - mu) * rstd * gam4.x + bet4.x;
            hn.y = (u4.y - mu) * rstd * gam4.y + bet4.y;
            hn.z = (u4.z - mu) * rstd * gam4.z + bet4.z;
            hn.w = (u4.w - mu) * rstd * gam4.w + bet4.w;
            if (tid < 64) {
                *(float4*)&hsA[l * 4] = hn;
                if ((l >> 4) == p) {
                    *(float4*)(ybA + (size_t)t * H + l * 4) = hn;
                    if (t == T - 1) {
                        *(float4*)(out + (size_t)NB * T * H + (size_t)rowA * H + l * 4) = hn;
                        float4 c4 = *(const float4*)&csA[l * 4];
                        *(float4*)(out + (size_t)NB * T * H + (size_t)NB * H + (size_t)rowA * H + l * 4) = c4;
                    }
                }
            } else {
                *(float4*)&hsB[l * 4] = hn;
                if ((l >> 4) == p) {
                    *(float4*)(ybB + (size_t)t * H + l * 4) = hn;
                    if (t == T - 1) {
                        *(float4*)(out + (size_t)NB * T * H + (size_t)rowB * H + l * 4) = hn;
                        float4 c4 = *(const float4*)&csB[l * 4];
                        *(float4*)(out + (size_t)NB * T * H + (size_t)NB * H + (size_t)rowB * H + l * 4) = c4;
                    }
                }
            }
        }
        __syncthreads();   // hsA/hsB ready for next step's P1
    }
}

extern "C" void kernel_launch(void* const* d_in, const int* in_sizes, int n_in,
                              void* d_out, int out_size, void* d_ws, size_t ws_size,
                              hipStream_t stream) {
    (void)in_sizes; (void)n_in; (void)out_size;
    if (ws_size < WS_NEEDED) return;

    const float* x     = (const float*)d_in[0];
    const float* Wi    = (const float*)d_in[1];
    const float* bi    = (const float*)d_in[2];
    const float* Wf    = (const float*)d_in[3];
    const float* bf    = (const float*)d_in[4];
    const float* Wc    = (const float*)d_in[5];
    const float* bc    = (const float*)d_in[6];
    const float* Wo    = (const float*)d_in[7];
    const float* bo    = (const float*)d_in[8];
    const float* Ui    = (const float*)d_in[9];
    const float* Uf    = (const float*)d_in[10];
    const float* Uc    = (const float*)d_in[11];
    const float* Uo    = (const float*)d_in[12];
    const float* K1    = (const float*)d_in[13];
    const float* kb1   = (const float*)d_in[14];
    const float* K2    = (const float*)d_in[15];
    const float* kb2   = (const float*)d_in[16];
    const float* gamma = (const float*)d_in[17];
    const float* beta  = (const float*)d_in[18];
    float* out = (float*)d_out;

    scan_kernel<<<dim3(PAIRS * NP), dim3(512), 0, stream>>>(
        x, Wi, bi, Wf, bf, Wc, bc, Wo, bo,
        Ui, Uf, Uc, Uo, K1, kb1, K2, kb2, gamma, beta, out,
        (unsigned long long*)d_ws);
}

// Round 6
// 16128.505 us; speedup vs baseline: 1.9366x; 1.6451x over previous
//
#include <hip/hip_runtime.h>

#define B 64
#define T 2048
#define D 128
#define H 256
#define H2 512
#define NP 4
#define CHUNK 8

// workspace: per row 1536 u64 tagged slots:
//   [0..255] c | [256..511] o | [512..1535] hpre (4 parts x 256 partials)
// value = low 32 bits (float bits), seq tag = high 32 bits.
#define ROW_U64 1536
#define WS_NEEDED ((size_t)B * ROW_U64 * 8)
#define SPIN_LIM (1 << 20)

__device__ __forceinline__ float sigmoid_f(float x) { return 1.f / (1.f + __expf(-x)); }
__device__ __forceinline__ float tanh_f(float x) {
    float e = __expf(2.f * x);
    return 1.f - 2.f / (e + 1.f);
}
__device__ __forceinline__ unsigned long long pack_tag(float v, unsigned int tag) {
    return ((unsigned long long)tag << 32) | (unsigned long long)__float_as_uint(v);
}
__device__ __forceinline__ float poll_tagged(const unsigned long long* __restrict__ ptr,
                                             unsigned int tag, bool& alive) {
    unsigned long long v;
    if (alive) {
        int cnt = 0;
        do {
            v = __hip_atomic_load(ptr, __ATOMIC_RELAXED, __HIP_MEMORY_SCOPE_AGENT);
            if ((unsigned int)(v >> 32) == tag)
                return __uint_as_float((unsigned int)v);
        } while (++cnt < SPIN_LIM);
        alive = false;   // latch: never spin again, accept wrong data over a hang
    }
    v = __hip_atomic_load(ptr, __ATOMIC_RELAXED, __HIP_MEMORY_SCOPE_AGENT);
    return __uint_as_float((unsigned int)v);
}

#define FMA4(A_, S_, W_) \
    A_.x = fmaf(S_, W_.x, A_.x); A_.y = fmaf(S_, W_.y, A_.y); \
    A_.z = fmaf(S_, W_.z, A_.z); A_.w = fmaf(S_, W_.w, A_.w);

// 256 blocks = 64 rows x 4 column-parts; 512 threads; 1 block/CU (LDS-forced).
// R3 topology (best measured). This revision shortens the per-step chain:
//  - K1 done as 4-thread/output quad-shuffle (no dump/bar/16-deep reduce)
//  - K2 transposed in LDS (pad 132), 2-thread/output, 1 shuffle, publish hpre
//    partial IMMEDIATELY, poll remotes in the same phase
//  - barriers/step 9 -> 7
#define K2P 132   // padded k-stride for transposed K2 (conflict-free b128)

__global__ __launch_bounds__(512, 2) void scan_kernel(
    const float* __restrict__ x,
    const float* __restrict__ Wi, const float* __restrict__ bi,
    const float* __restrict__ Wf, const float* __restrict__ bf,
    const float* __restrict__ Wc, const float* __restrict__ bc,
    const float* __restrict__ Wo, const float* __restrict__ bo,
    const float* __restrict__ Ui, const float* __restrict__ Uf,
    const float* __restrict__ Uc, const float* __restrict__ Uo,
    const float* __restrict__ K1, const float* __restrict__ kb1,
    const float* __restrict__ K2, const float* __restrict__ kb2,
    const float* __restrict__ gamma, const float* __restrict__ beta,
    float* __restrict__ out,
    unsigned long long* __restrict__ ws)
{
    const int bid = blockIdx.x;
    const int b   = bid >> 2;
    const int p   = bid & 3;
    const int tid = threadIdx.x;

    __shared__ float k2t[256 * K2P];      // 132 KB: K2 transposed [outcol][k], k = local row
    __shared__ float xw[CHUNK][256];      // 8 KB
    __shared__ float red[2048];           // 8 KB (phase P + phase G dumps)
    __shared__ float hs[H], cs[H], os[H], us[H], ts[128];

    // ---- roles ----
    const int kq  = tid >> 6;                              // 0..7 (wave)
    const int grp = tid & 63;
    const int gG  = grp >> 4;                              // gate 0..3
    const int jG  = (grp & 15) * 4;                        // col-4 within part

    const float* Ug = (gG == 0) ? Ui : (gG == 1) ? Uf : (gG == 2) ? Uc : Uo;
    const float* Wg = (gG == 0) ? Wi : (gG == 1) ? Wf : (gG == 2) ? Wc : Wo;

    // ---- register-resident U quarter (as R3) ----
    float4 uw[32];                                    // U: 32 k x 4 cols
    #pragma unroll
    for (int k = 0; k < 32; ++k)
        uw[k] = *(const float4*)(Ug + (size_t)(kq * 32 + k) * H + p * 64 + jG);

    // ---- register-resident K1 quarter, per-output layout ----
    // thread: col = tid>>2 (0..127 -> K1 col p*128+col), ks = tid&3 (k-range ks*64..+64)
    const int c1  = tid >> 2;
    const int ks  = tid & 3;
    float4 k1w[16];                                   // 16 x (4 consecutive k) x 1 col
    #pragma unroll
    for (int i = 0; i < 16; ++i) {
        float4 v;
        v.x = K1[(size_t)(ks * 64 + i * 4 + 0) * H2 + p * 128 + c1];
        v.y = K1[(size_t)(ks * 64 + i * 4 + 1) * H2 + p * 128 + c1];
        v.z = K1[(size_t)(ks * 64 + i * 4 + 2) * H2 + p * 128 + c1];
        v.w = K1[(size_t)(ks * 64 + i * 4 + 3) * H2 + p * 128 + c1];
        k1w[i] = v;
    }

    // ---- K2 row-slice -> LDS, TRANSPOSED with pad ----
    // k2t[c*K2P + k] = K2[(p*128+k)*H + c]
    for (int idx = tid; idx < 128 * 256; idx += 512) {
        int k = idx >> 8, c = idx & 255;              // global read coalesced over c
        k2t[c * K2P + k] = K2[(size_t)(p * 128 + k) * H + c];
    }

    // ---- per-role constants ----
    float bcat = 0.f;
    const float kb1r = kb1[p * 128 + c1];             // for K1 quad (ks==0 lanes use it)
    const float kb2r = kb2[tid >> 1];                 // for K2 even lanes
    float4 gam4, bet4;
    if (tid < 256) {
        const int g = tid >> 6, jj = tid & 63;
        const float* bp = (g == 0) ? bi : (g == 1) ? bf : (g == 2) ? bc : bo;
        bcat = bp[p * 64 + jj];
    }
    if (tid < 64) {
        gam4 = *(const float4*)(gamma + tid * 4);
        bet4 = *(const float4*)(beta + tid * 4);
    }

    if (tid < 256) hs[tid] = 0.f;
    float c_reg = 0.f;                   // lane j (tid<64) carries c[p*64+j]

    const float* xrow = x + (size_t)b * T * D;
    float* yb = out + (size_t)b * T * H;
    unsigned long long* rowp  = ws + (size_t)b * ROW_U64;
    unsigned long long* slotC = rowp;
    unsigned long long* slotO = rowp + 256;
    unsigned long long* slotH = rowp + 512;            // [part*256 + j]
    const int dqu = __builtin_amdgcn_readfirstlane(kq);   // uniform d-slice for x s_loads

    bool alive = true;
    __syncthreads();

    for (int t = 0; t < T; ++t) {
        const int tt8 = t & (CHUNK - 1);
        const unsigned int seq = (unsigned int)(t + 1);

        // ============ phase P: x@W for 8 steps (once per chunk; W streamed) ============
        if (tt8 == 0) {
            const float* Wp = Wg + p * 64 + jG;
            #pragma unroll
            for (int pass = 0; pass < 2; ++pass) {
                float4 acc[4];
                #pragma unroll
                for (int r = 0; r < 4; ++r) acc[r] = make_float4(0.f, 0.f, 0.f, 0.f);
                #pragma unroll 4
                for (int dd = 0; dd < 16; ++dd) {
                    const int d = dqu * 16 + dd;
                    float4 w = *(const float4*)(Wp + (size_t)d * H);
                    #pragma unroll
                    for (int r = 0; r < 4; ++r) {
                        float xv = xrow[(size_t)(t + pass * 4 + r) * D + d];  // uniform -> s_load
                        FMA4(acc[r], xv, w);
                    }
                }
                #pragma unroll
                for (int r = 0; r < 4; ++r) {
                    *(float4*)&red[kq * 256 + grp * 4] = acc[r];
                    __syncthreads();
                    if (tid < 256) {
                        float s = bcat;
                        #pragma unroll
                        for (int q = 0; q < 8; ++q) s += red[q * 256 + tid];
                        xw[pass * 4 + r][tid] = s;
                    }
                    __syncthreads();
                }
            }
        }

        // ============ G: gate preacts from register-resident U (dump) ============
        {
            float4 a = make_float4(0.f, 0.f, 0.f, 0.f);
            #pragma unroll
            for (int k4 = 0; k4 < 8; ++k4) {
                float4 hv = *(const float4*)&hs[kq * 32 + k4 * 4];
                FMA4(a, hv.x, uw[k4 * 4 + 0]);
                FMA4(a, hv.y, uw[k4 * 4 + 1]);
                FMA4(a, hv.z, uw[k4 * 4 + 2]);
                FMA4(a, hv.w, uw[k4 * 4 + 3]);
            }
            *(float4*)&red[kq * 256 + grp * 4] = a;
        }
        __syncthreads();

        // ============ cell + publish (tid<64) ; poll remote {c,o} (tid 64..447) ============
        if (tid < 64) {
            const int j = tid;
            float si = xw[tt8][j],        sf = xw[tt8][64 + j],
                  sg = xw[tt8][128 + j],  so = xw[tt8][192 + j];
            #pragma unroll
            for (int q = 0; q < 8; ++q) {
                si += red[q * 256 + j];
                sf += red[q * 256 + 64 + j];
                sg += red[q * 256 + 128 + j];
                so += red[q * 256 + 192 + j];
            }
            float iv = sigmoid_f(si), fv = sigmoid_f(sf);
            float gv = tanh_f(sg),    ov = sigmoid_f(so);
            float c = fmaf(fv, c_reg, iv * gv);
            c_reg = c;
            cs[p * 64 + j] = c;
            os[p * 64 + j] = ov;
            __hip_atomic_store(slotC + p * 64 + j, pack_tag(c, seq),
                               __ATOMIC_RELAXED, __HIP_MEMORY_SCOPE_AGENT);
            __hip_atomic_store(slotO + p * 64 + j, pack_tag(ov, seq),
                               __ATOMIC_RELAXED, __HIP_MEMORY_SCOPE_AGENT);
        } else if (tid < 448) {
            const int idx = tid - 64;                      // 0..383
            if (idx < 192) {
                const int q  = (p + 1 + (idx >> 6)) & 3;   // remote part
                const int gj = q * 64 + (idx & 63);
                cs[gj] = poll_tagged(slotC + gj, seq, alive);
            } else {
                const int i2 = idx - 192;
                const int q  = (p + 1 + (i2 >> 6)) & 3;
                const int gj = q * 64 + (i2 & 63);
                os[gj] = poll_tagged(slotO + gj, seq, alive);
            }
        }
        __syncthreads();

        // ============ K1+ts fused: 4 threads/output, quad shuffle ============
        {
            float a = 0.f;
            #pragma unroll
            for (int i = 0; i < 16; ++i) {
                float4 cv = *(const float4*)&cs[ks * 64 + i * 4];
                a += cv.x * k1w[i].x + cv.y * k1w[i].y
                   + cv.z * k1w[i].z + cv.w * k1w[i].w;
            }
            a += __shfl_xor(a, 1);
            a += __shfl_xor(a, 2);
            if (ks == 0) ts[c1] = tanh_f(a + kb1r);
        }
        __syncthreads();

        // ============ K2 fused: 2 threads/output, publish partial NOW, poll, u ============
        {
            const int col = tid >> 1, kh = tid & 1;
            float a = 0.f;
            #pragma unroll
            for (int i = 0; i < 16; ++i) {
                float4 tv = *(const float4*)&ts[kh * 64 + i * 4];
                float4 wv = *(const float4*)&k2t[col * K2P + kh * 64 + i * 4];
                a += tv.x * wv.x + tv.y * wv.y + tv.z * wv.z + tv.w * wv.w;
            }
            a += __shfl_xor(a, 1);                 // both kh lanes now hold full partial
            if (kh == 0) {
                __hip_atomic_store(slotH + p * 256 + col, pack_tag(a, seq),
                                   __ATOMIC_RELAXED, __HIP_MEMORY_SCOPE_AGENT);
                const unsigned long long* q1 = slotH + (((p + 1) & 3) << 8) + col;
                const unsigned long long* q2 = slotH + (((p + 2) & 3) << 8) + col;
                const unsigned long long* q3 = slotH + (((p + 3) & 3) << 8) + col;
                unsigned long long v1 = 0, v2 = 0, v3 = 0;
                bool d1 = false, d2 = false, d3 = false;
                int cnt = 0;
                const int lim = alive ? SPIN_LIM : 2;
                while (true) {   // 3 loads in flight per iteration
                    if (!d1) v1 = __hip_atomic_load(q1, __ATOMIC_RELAXED, __HIP_MEMORY_SCOPE_AGENT);
                    if (!d2) v2 = __hip_atomic_load(q2, __ATOMIC_RELAXED, __HIP_MEMORY_SCOPE_AGENT);
                    if (!d3) v3 = __hip_atomic_load(q3, __ATOMIC_RELAXED, __HIP_MEMORY_SCOPE_AGENT);
                    d1 = d1 | ((unsigned int)(v1 >> 32) == seq);
                    d2 = d2 | ((unsigned int)(v2 >> 32) == seq);
                    d3 = d3 | ((unsigned int)(v3 >> 32) == seq);
                    if (d1 & d2 & d3) break;
                    if (++cnt > lim) { alive = false; break; }
                }
                float hp = a + __uint_as_float((unsigned int)v1)
                             + __uint_as_float((unsigned int)v2)
                             + __uint_as_float((unsigned int)v3) + kb2r;
                us[col] = os[col] * tanh_f(hp);
            }
        }
        __syncthreads();

        // ============ LayerNorm (replicated; full u local) ============
        if (tid < 64) {
            float4 u4 = *(const float4*)&us[tid * 4];
            float s1 = u4.x + u4.y + u4.z + u4.w;
            float s2 = u4.x * u4.x + u4.y * u4.y + u4.z * u4.z + u4.w * u4.w;
            #pragma unroll
            for (int off = 32; off > 0; off >>= 1) {
                s1 += __shfl_xor(s1, off);
                s2 += __shfl_xor(s2, off);
            }
            float mu   = s1 * (1.f / 256.f);
            float var  = fmaf(-mu, mu, s2 * (1.f / 256.f));
            float rstd = rsqrtf(var + 1e-5f);
            float4 hn;
            hn.x = (u4.x - mu) * rstd * gam4.x + bet4.x;
            hn.y = (u4.y - mu) * rstd * gam4.y + bet4.y;
            hn.z = (u4.z - mu) * rstd * gam4.z + bet4.z;
            hn.w = (u4.w - mu) * rstd * gam4.w + bet4.w;
            *(float4*)&hs[tid * 4] = hn;
            if ((tid >> 4) == p) {   // own column slice only
                *(float4*)(yb + (size_t)t * H + tid * 4) = hn;
                if (t == T - 1) {
                    *(float4*)(out + (size_t)B * T * H + (size_t)b * H + tid * 4) = hn;
                    float4 c4 = *(const float4*)&cs[tid * 4];
                    *(float4*)(out + (size_t)B * T * H + (size_t)B * H + (size_t)b * H + tid * 4) = c4;
                }
            }
        }
        __syncthreads();   // hs ready for next step's G
    }
}

extern "C" void kernel_launch(void* const* d_in, const int* in_sizes, int n_in,
                              void* d_out, int out_size, void* d_ws, size_t ws_size,
                              hipStream_t stream) {
    (void)in_sizes; (void)n_in; (void)out_size;
    if (ws_size < WS_NEEDED) return;

    const float* x     = (const float*)d_in[0];
    const float* Wi    = (const float*)d_in[1];
    const float* bi    = (const float*)d_in[2];
    const float* Wf    = (const float*)d_in[3];
    const float* bf    = (const float*)d_in[4];
    const float* Wc    = (const float*)d_in[5];
    const float* bc    = (const float*)d_in[6];
    const float* Wo    = (const float*)d_in[7];
    const float* bo    = (const float*)d_in[8];
    const float* Ui    = (const float*)d_in[9];
    const float* Uf    = (const float*)d_in[10];
    const float* Uc    = (const float*)d_in[11];
    const float* Uo    = (const float*)d_in[12];
    const float* K1    = (const float*)d_in[13];
    const float* kb1   = (const float*)d_in[14];
    const float* K2    = (const float*)d_in[15];
    const float* kb2   = (const float*)d_in[16];
    const float* gamma = (const float*)d_in[17];
    const float* beta  = (const float*)d_in[18];
    float* out = (float*)d_out;

    scan_kernel<<<dim3(B * NP), dim3(512), 0, stream>>>(
        x, Wi, bi, Wf, bf, Wc, bc, Wo, bo,
        Ui, Uf, Uc, Uo, K1, kb1, K2, kb2, gamma, beta, out,
        (unsigned long long*)d_ws);
}